// Round 2
// baseline (458.580 us; speedup 1.0000x reference)
//
#include <hip/hip_runtime.h>

#define B_  32
#define IN_ 4096
#define N_  2048
#define P_  128
#define M_  256
#define D_  10

typedef _Float16 f16;
typedef f16  f16x4   __attribute__((ext_vector_type(4)));
typedef f16  f16x8   __attribute__((ext_vector_type(8)));
typedef float f32x4  __attribute__((ext_vector_type(4)));
typedef float floatx4 __attribute__((ext_vector_type(4)));
typedef int   intx4   __attribute__((ext_vector_type(4)));

union F8 { f16x8 v; f16x4 h[2]; };

__device__ __forceinline__ float sigmoidf_(float z) {
    return __builtin_amdgcn_rcpf(1.0f + __expf(-z));
}

// One block = one neuron n. 256 threads = 4 waves. 5 blocks/CU target.
// LDS overlay (31888 B):
//   [0      .. 8192 )  s_bits [32][128] f16, swizzled      } dead after last MFMA
//   [8192   .. 24576)  s_keys [64][128] f16, swizzled      }
//   [0      .. 16384)  s_w    [32][256] f16, swizzled  (overlays the two above)
//   [24576  .. 30736)  s_val  [256][12] f16 + 8 slack (col10=1 denom, col11=0)
//   [30736  .. 30864)  s_bsq  [32] f32
//   [30864  .. 31888)  s_ksq  [256] f32
// Swizzle: element (row,p) at 4-unit u' = (p>>2) ^ (row&15), low bits p&3.
// K-fragment map phi(lhi,e)=16*(e>>2)+4*lhi+(e&3) applied to both A and B.
// C layout (verified): col=lane&15, row=(lane>>4)*4+reg.
__global__ __launch_bounds__(256, 5) void vgram_kernel(
    const float* __restrict__ x, const int* __restrict__ idx_a, const int* __restrict__ idx_b,
    const float* __restrict__ keys_raw, const float* __restrict__ values, float* __restrict__ out)
{
    const int n   = blockIdx.x;
    const int t   = threadIdx.x;
    const int l   = t & 63;
    const int wv  = t >> 6;
    const int lhi = l >> 4;
    const int l15 = l & 15;

    __shared__ __align__(16) unsigned char smem[31888];
    f16 (*s_bits)[P_] = (f16 (*)[P_])(smem);
    f16 (*s_keys)[P_] = (f16 (*)[P_])(smem + 8192);
    f16 (*s_w)[M_]    = (f16 (*)[M_])(smem);
    f16  *s_val       = (f16*)(smem + 24576);
    float *s_bsq      = (float*)(smem + 30736);
    float *s_ksq      = (float*)(smem + 30864);

    const float* kb_base = keys_raw + (size_t)n * (M_ * P_);

    // ---- issue chunk-0 key prefetch FIRST: latency hides under phases 0/1 ----
    floatx4 pf[8];
    #pragma unroll
    for (int it = 0; it < 8; ++it)
        pf[it] = *(const floatx4*)(kb_base + (it * 256 + t) * 4);

    // ---- phase 0: values staging (stride 12, ones col 10, zero col 11) ----
    {
        const float* vb = values + (size_t)n * (M_ * D_);
        #pragma unroll
        for (int it = 0; it < 10; ++it) {
            int f = it * 256 + t;            // 0..2559, coalesced
            float vvv = vb[f];
            int m = f / 10, d = f - m * 10;
            s_val[m * 12 + d] = (f16)vvv;
        }
        s_val[t * 12 + 10] = (f16)1.0f;      // ones column -> softmax denominator
        s_val[t * 12 + 11] = (f16)0.0f;
        if (t < 8) s_val[3072 + t] = (f16)0.0f;   // slack for row-255 overreads
    }

    // ---- phase 1: bits = sigmoid(x[b,ia]-x[b,ib]), b_sq (rounded-consistent) ----
    #pragma unroll
    for (int it = 0; it < 4; ++it) {
        int sig = it * 256 + t;              // b = sig>>5, q = sig&31
        int b = sig >> 5, q = sig & 31;
        intx4 ia4 = *(const intx4*)(idx_a + n * P_ + q * 4);
        intx4 ib4 = *(const intx4*)(idx_b + n * P_ + q * 4);
        const float* xr = x + b * IN_;
        float partial = 0.f;
        f16x4 hh;
        #pragma unroll
        for (int r = 0; r < 4; ++r) {
            float z = xr[ia4[r]] - xr[ib4[r]];
            f16 hs = (f16)sigmoidf_(z);
            float hf = (float)hs;
            partial += hf * hf;
            hh[r] = hs;
        }
        *(f16x4*)&s_bits[b][((q ^ (b & 15)) << 2)] = hh;
        #pragma unroll
        for (int off = 1; off < 32; off <<= 1)
            partial += __shfl_xor(partial, off, 32);
        if ((t & 31) == 0) s_bsq[b] = partial;
    }

    f32x4 acc[4][2] = {};   // [chunk][row-tile]

    #pragma unroll
    for (int ck = 0; ck < 4; ++ck) {
        // ---- consume prefetched chunk: sigmoid + f16 + k_sq; interleave next-chunk issue ----
        #pragma unroll
        for (int it = 0; it < 8; ++it) {
            int f = it * 256 + t;
            int m = f >> 5, q = f & 31;
            float partial = 0.f;
            f16x4 hh;
            #pragma unroll
            for (int r = 0; r < 4; ++r) {
                f16 hs = (f16)sigmoidf_(pf[it][r]);
                float hf = (float)hs;
                partial += hf * hf;
                hh[r] = hs;
            }
            if (ck < 3)   // reuse pf[it] right after consumption -> loads pipeline
                pf[it] = *(const floatx4*)(kb_base + (ck + 1) * (64 * P_) + (it * 256 + t) * 4);
            *(f16x4*)&s_keys[m][((q ^ (m & 15)) << 2)] = hh;
            #pragma unroll
            for (int off = 1; off < 32; off <<= 1)
                partial += __shfl_xor(partial, off, 32);
            if ((t & 31) == 0) s_ksq[ck * 64 + m] = partial;
        }
        __syncthreads();

        // ---- dots MFMA: wave wv owns m-cols 16*wv..16*wv+15 of the chunk ----
        {
            int mrow = wv * 16 + l15;        // mrow&15 == l15
            #pragma unroll
            for (int ks = 0; ks < 4; ++ks) {
                int u1 = (ks * 8 + lhi) ^ l15;
                int u2 = u1 ^ 4;
                F8 bfrag, a0, a1;
                bfrag.h[0] = *(const f16x4*)&s_keys[mrow][u1 << 2];
                bfrag.h[1] = *(const f16x4*)&s_keys[mrow][u2 << 2];
                a0.h[0] = *(const f16x4*)&s_bits[l15][u1 << 2];
                a0.h[1] = *(const f16x4*)&s_bits[l15][u2 << 2];
                a1.h[0] = *(const f16x4*)&s_bits[16 + l15][u1 << 2];
                a1.h[1] = *(const f16x4*)&s_bits[16 + l15][u2 << 2];
                acc[ck][0] = __builtin_amdgcn_mfma_f32_16x16x32_f16(a0.v, bfrag.v, acc[ck][0], 0, 0, 0);
                acc[ck][1] = __builtin_amdgcn_mfma_f32_16x16x32_f16(a1.v, bfrag.v, acc[ck][1], 0, 0, 0);
            }
        }
        __syncthreads();   // protect s_keys overwrite (and s_bits/s_w overlay after last ck)
    }

    // ---- epilogue 1: dist -> w = exp(-dist) into s_w (f16, swizzled; overlays bits/keys) ----
    #pragma unroll
    for (int ck = 0; ck < 4; ++ck) {
        int mg = ck * 64 + wv * 16 + l15;
        float ksq = s_ksq[mg];
        #pragma unroll
        for (int rt = 0; rt < 2; ++rt) {
            #pragma unroll
            for (int reg = 0; reg < 4; ++reg) {
                int b = rt * 16 + lhi * 4 + reg;      // C row map (verified)
                float dots = acc[ck][rt][reg];
                float d2 = s_bsq[b] + ksq - 2.f * dots;
                d2 = fmaxf(d2, 0.f) + 1e-12f;
                float dist = sqrtf(d2);
                float wexp = __expf(-dist);           // dist>=0 -> (0,1], no max-sub needed
                int u = mg >> 2;
                s_w[b][((u ^ (b & 15)) << 2) | (mg & 3)] = (f16)wexp;
            }
        }
    }
    __syncthreads();

    // ---- epilogue 2 (wave 0): out = (w @ [values|1]) / sum ----
    if (wv == 0) {
        f32x4 c2[2] = {};
        #pragma unroll
        for (int ks2 = 0; ks2 < 8; ++ks2) {
            F8 bfrag;                                  // B: values, col d = l15, k = m
            #pragma unroll
            for (int e = 0; e < 8; ++e) {
                int mm = ks2 * 32 + (e >> 2) * 16 + lhi * 4 + (e & 3);
                bfrag.h[e >> 2][e & 3] = s_val[mm * 12 + l15];
            }
            #pragma unroll
            for (int rt = 0; rt < 2; ++rt) {
                int b = rt * 16 + l15;                 // A row: swz key == l15
                int u1 = (ks2 * 8 + lhi) ^ l15;
                int u2 = u1 ^ 4;
                F8 af;
                af.h[0] = *(const f16x4*)&s_w[b][u1 << 2];
                af.h[1] = *(const f16x4*)&s_w[b][u2 << 2];
                c2[rt] = __builtin_amdgcn_mfma_f32_16x16x32_f16(af.v, bfrag.v, c2[rt], 0, 0, 0);
            }
        }
        #pragma unroll
        for (int rt = 0; rt < 2; ++rt) {
            #pragma unroll
            for (int reg = 0; reg < 4; ++reg) {
                float sum = __shfl(c2[rt][reg], (l & 48) | 10, 64);  // ones-column
                float rs = 1.0f / sum;
                if (l15 < 10) {
                    int b = rt * 16 + lhi * 4 + reg;
                    out[((size_t)b * N_ + n) * D_ + l15] = c2[rt][reg] * rs;
                }
            }
        }
    }
}

extern "C" void kernel_launch(void* const* d_in, const int* in_sizes, int n_in,
                              void* d_out, int out_size, void* d_ws, size_t ws_size,
                              hipStream_t stream) {
    const float* x    = (const float*)d_in[0];
    const int*   ia   = (const int*)d_in[1];
    const int*   ib   = (const int*)d_in[2];
    const float* keys = (const float*)d_in[3];
    const float* vals = (const float*)d_in[4];
    float* o = (float*)d_out;
    vgram_kernel<<<dim3(N_), dim3(256), 0, stream>>>(x, ia, ib, keys, vals, o);
}

// Round 3
// 424.528 us; speedup vs baseline: 1.0802x; 1.0802x over previous
//
#include <hip/hip_runtime.h>

#define B_  32
#define IN_ 4096
#define N_  2048
#define P_  128
#define M_  256
#define D_  10

typedef _Float16 f16;
typedef f16  f16x4   __attribute__((ext_vector_type(4)));
typedef f16  f16x8   __attribute__((ext_vector_type(8)));
typedef float f32x4  __attribute__((ext_vector_type(4)));
typedef float floatx4 __attribute__((ext_vector_type(4)));
typedef int   intx4   __attribute__((ext_vector_type(4)));

union F8 { f16x8 v; f16x4 h[2]; };

__device__ __forceinline__ float sigmoidf_(float z) {
    return __builtin_amdgcn_rcpf(1.0f + __expf(-z));
}

// One block = one neuron n. 256 threads = 4 waves. 4 blocks/CU (VGPR cap 128
// so the pf[8] chunk prefetch stays register-resident -- at (256,5)/cap~96 it
// spilled to scratch: WRITE_SIZE 4->59 MB, dur +20%).
// LDS overlay (31888 B):
//   [0      .. 8192 )  s_bits [32][128] f16, swizzled      } dead after last MFMA
//   [8192   .. 24576)  s_keys [64][128] f16, swizzled      }
//   [0      .. 16384)  s_w    [32][256] f16, swizzled  (overlays the two above)
//   [24576  .. 30736)  s_val  [256][12] f16 + 8 slack (col10=1 denom, col11=0)
//   [30736  .. 30864)  s_bsq  [32] f32
//   [30864  .. 31888)  s_ksq  [256] f32
// Swizzle: element (row,p) at 4-unit u' = (p>>2) ^ (row&15), low bits p&3.
// K-fragment map phi(lhi,e)=16*(e>>2)+4*lhi+(e&3) applied to both A and B.
// C layout (verified): col=lane&15, row=(lane>>4)*4+reg.
__global__ __launch_bounds__(256, 4) void vgram_kernel(
    const float* __restrict__ x, const int* __restrict__ idx_a, const int* __restrict__ idx_b,
    const float* __restrict__ keys_raw, const float* __restrict__ values, float* __restrict__ out)
{
    const int n   = blockIdx.x;
    const int t   = threadIdx.x;
    const int l   = t & 63;
    const int wv  = t >> 6;
    const int lhi = l >> 4;
    const int l15 = l & 15;

    __shared__ __align__(16) unsigned char smem[31888];
    f16 (*s_bits)[P_] = (f16 (*)[P_])(smem);
    f16 (*s_keys)[P_] = (f16 (*)[P_])(smem + 8192);
    f16 (*s_w)[M_]    = (f16 (*)[M_])(smem);
    f16  *s_val       = (f16*)(smem + 24576);
    float *s_bsq      = (float*)(smem + 30736);
    float *s_ksq      = (float*)(smem + 30864);

    const float* kb_base = keys_raw + (size_t)n * (M_ * P_);

    // ---- issue chunk-0 key prefetch FIRST: latency hides under phases 0/1 ----
    floatx4 pf[8];
    #pragma unroll
    for (int it = 0; it < 8; ++it)
        pf[it] = *(const floatx4*)(kb_base + (it * 256 + t) * 4);

    // ---- phase 0: values staging (stride 12, ones col 10, zero col 11) ----
    {
        const float* vb = values + (size_t)n * (M_ * D_);
        #pragma unroll
        for (int it = 0; it < 10; ++it) {
            int f = it * 256 + t;            // 0..2559, coalesced
            float vvv = vb[f];
            int m = f / 10, d = f - m * 10;
            s_val[m * 12 + d] = (f16)vvv;
        }
        s_val[t * 12 + 10] = (f16)1.0f;      // ones column -> softmax denominator
        s_val[t * 12 + 11] = (f16)0.0f;
        if (t < 8) s_val[3072 + t] = (f16)0.0f;   // slack for row-255 overreads
    }

    // ---- phase 1: bits = sigmoid(x[b,ia]-x[b,ib]), b_sq (rounded-consistent) ----
    #pragma unroll
    for (int it = 0; it < 4; ++it) {
        int sig = it * 256 + t;              // b = sig>>5, q = sig&31
        int b = sig >> 5, q = sig & 31;
        intx4 ia4 = *(const intx4*)(idx_a + n * P_ + q * 4);
        intx4 ib4 = *(const intx4*)(idx_b + n * P_ + q * 4);
        const float* xr = x + b * IN_;
        float partial = 0.f;
        f16x4 hh;
        #pragma unroll
        for (int r = 0; r < 4; ++r) {
            float z = xr[ia4[r]] - xr[ib4[r]];
            f16 hs = (f16)sigmoidf_(z);
            float hf = (float)hs;
            partial += hf * hf;
            hh[r] = hs;
        }
        *(f16x4*)&s_bits[b][((q ^ (b & 15)) << 2)] = hh;
        #pragma unroll
        for (int off = 1; off < 32; off <<= 1)
            partial += __shfl_xor(partial, off, 32);
        if ((t & 31) == 0) s_bsq[b] = partial;
    }

    f32x4 acc[4][2] = {};   // [chunk][row-tile]

    #pragma unroll
    for (int ck = 0; ck < 4; ++ck) {
        // ---- consume prefetched chunk: sigmoid + f16 + k_sq; interleave next-chunk issue ----
        #pragma unroll
        for (int it = 0; it < 8; ++it) {
            int f = it * 256 + t;
            int m = f >> 5, q = f & 31;
            float partial = 0.f;
            f16x4 hh;
            #pragma unroll
            for (int r = 0; r < 4; ++r) {
                f16 hs = (f16)sigmoidf_(pf[it][r]);
                float hf = (float)hs;
                partial += hf * hf;
                hh[r] = hs;
            }
            if (ck < 3)   // reuse pf[it] right after consumption -> loads pipeline
                pf[it] = *(const floatx4*)(kb_base + (ck + 1) * (64 * P_) + (it * 256 + t) * 4);
            *(f16x4*)&s_keys[m][((q ^ (m & 15)) << 2)] = hh;
            #pragma unroll
            for (int off = 1; off < 32; off <<= 1)
                partial += __shfl_xor(partial, off, 32);
            if ((t & 31) == 0) s_ksq[ck * 64 + m] = partial;
        }
        __syncthreads();

        // ---- dots MFMA: wave wv owns m-cols 16*wv..16*wv+15 of the chunk ----
        {
            int mrow = wv * 16 + l15;        // mrow&15 == l15
            #pragma unroll
            for (int ks = 0; ks < 4; ++ks) {
                int u1 = (ks * 8 + lhi) ^ l15;
                int u2 = u1 ^ 4;
                F8 bfrag, a0, a1;
                bfrag.h[0] = *(const f16x4*)&s_keys[mrow][u1 << 2];
                bfrag.h[1] = *(const f16x4*)&s_keys[mrow][u2 << 2];
                a0.h[0] = *(const f16x4*)&s_bits[l15][u1 << 2];
                a0.h[1] = *(const f16x4*)&s_bits[l15][u2 << 2];
                a1.h[0] = *(const f16x4*)&s_bits[16 + l15][u1 << 2];
                a1.h[1] = *(const f16x4*)&s_bits[16 + l15][u2 << 2];
                acc[ck][0] = __builtin_amdgcn_mfma_f32_16x16x32_f16(a0.v, bfrag.v, acc[ck][0], 0, 0, 0);
                acc[ck][1] = __builtin_amdgcn_mfma_f32_16x16x32_f16(a1.v, bfrag.v, acc[ck][1], 0, 0, 0);
            }
        }
        __syncthreads();   // protect s_keys overwrite (and s_bits/s_w overlay after last ck)
    }

    // ---- epilogue 1: dist -> w = exp(-dist) into s_w (f16, swizzled; overlays bits/keys) ----
    #pragma unroll
    for (int ck = 0; ck < 4; ++ck) {
        int mg = ck * 64 + wv * 16 + l15;
        float ksq = s_ksq[mg];
        #pragma unroll
        for (int rt = 0; rt < 2; ++rt) {
            #pragma unroll
            for (int reg = 0; reg < 4; ++reg) {
                int b = rt * 16 + lhi * 4 + reg;      // C row map (verified)
                float dots = acc[ck][rt][reg];
                float d2 = s_bsq[b] + ksq - 2.f * dots;
                d2 = fmaxf(d2, 0.f) + 1e-12f;
                float dist = sqrtf(d2);
                float wexp = __expf(-dist);           // dist>=0 -> (0,1], no max-sub needed
                int u = mg >> 2;
                s_w[b][((u ^ (b & 15)) << 2) | (mg & 3)] = (f16)wexp;
            }
        }
    }
    __syncthreads();

    // ---- epilogue 2 (wave 0): out = (w @ [values|1]) / sum ----
    if (wv == 0) {
        f32x4 c2[2] = {};
        #pragma unroll
        for (int ks2 = 0; ks2 < 8; ++ks2) {
            F8 bfrag;                                  // B: values, col d = l15, k = m
            #pragma unroll
            for (int e = 0; e < 8; ++e) {
                int mm = ks2 * 32 + (e >> 2) * 16 + lhi * 4 + (e & 3);
                bfrag.h[e >> 2][e & 3] = s_val[mm * 12 + l15];
            }
            #pragma unroll
            for (int rt = 0; rt < 2; ++rt) {
                int b = rt * 16 + l15;                 // A row: swz key == l15
                int u1 = (ks2 * 8 + lhi) ^ l15;
                int u2 = u1 ^ 4;
                F8 af;
                af.h[0] = *(const f16x4*)&s_w[b][u1 << 2];
                af.h[1] = *(const f16x4*)&s_w[b][u2 << 2];
                c2[rt] = __builtin_amdgcn_mfma_f32_16x16x32_f16(af.v, bfrag.v, c2[rt], 0, 0, 0);
            }
        }
        #pragma unroll
        for (int rt = 0; rt < 2; ++rt) {
            #pragma unroll
            for (int reg = 0; reg < 4; ++reg) {
                float sum = __shfl(c2[rt][reg], (l & 48) | 10, 64);  // ones-column
                float rs = 1.0f / sum;
                if (l15 < 10) {
                    int b = rt * 16 + lhi * 4 + reg;
                    out[((size_t)b * N_ + n) * D_ + l15] = c2[rt][reg] * rs;
                }
            }
        }
    }
}

extern "C" void kernel_launch(void* const* d_in, const int* in_sizes, int n_in,
                              void* d_out, int out_size, void* d_ws, size_t ws_size,
                              hipStream_t stream) {
    const float* x    = (const float*)d_in[0];
    const int*   ia   = (const int*)d_in[1];
    const int*   ib   = (const int*)d_in[2];
    const float* keys = (const float*)d_in[3];
    const float* vals = (const float*)d_in[4];
    float* o = (float*)d_out;
    vgram_kernel<<<dim3(N_), dim3(256), 0, stream>>>(x, ia, ib, keys, vals, o);
}